// Round 2
// baseline (389.782 us; speedup 1.0000x reference)
//
#include <hip/hip_runtime.h>
#include <stdint.h>

// LSTMBaseline: 2-layer, 1-step LSTM (zero init state) + decoder on MI355X.
//   h0 = lstm(x; W_ih0, b_ih0+b_hh0)      M=16384, K=512,  H=1024
//   h1 = lstm(h0; W_ih1, b_ih1+b_hh1)     K=1024
//   out = h1 @ W_dec^T + b_dec            N=512
// Inputs/outputs are FLOAT32 (reference dtype). We stage f32 -> bf16 into
// LDS via registers and run bf16 MFMA (no fp32 MFMA on CDNA4); h0/h1 are
// stored bf16 in d_ws. Algebraic cuts: f-gate dead (c0=0), W_hh dead (h0=0).

typedef __attribute__((ext_vector_type(8))) __bf16 bf16x8;
typedef __attribute__((ext_vector_type(8))) unsigned short u16x8;
typedef __attribute__((ext_vector_type(4))) float f32x4;

#define BM 128
#define BK 64

__device__ __forceinline__ unsigned short f2b(float f) {
    unsigned int x = __builtin_bit_cast(unsigned int, f);
    x = x + 0x7FFFu + ((x >> 16) & 1u);   // RNE
    return (unsigned short)(x >> 16);
}
__device__ __forceinline__ float sigf(float x) { return 1.0f / (1.0f + __expf(-x)); }
__device__ __forceinline__ float tanh_safe(float x) {
    float a = fabsf(x);
    float e = __expf(-2.0f * a);
    float t = (1.0f - e) / (1.0f + e);
    return x < 0.0f ? -t : t;
}

// Copy one 8-element chunk into LDS as bf16. F32=1: src is 8 f32 (cvt);
// F32=0: src is 8 bf16 (raw 16B copy).
template <int F32>
__device__ __forceinline__ void stage_chunk(const void* src, unsigned short* dst) {
    if constexpr (F32) {
        const float* s = (const float*)src;
        f32x4 lo = *reinterpret_cast<const f32x4*>(s);
        f32x4 hi = *reinterpret_cast<const f32x4*>(s + 4);
        bf16x8 v;
        v[0] = (__bf16)lo[0]; v[1] = (__bf16)lo[1];
        v[2] = (__bf16)lo[2]; v[3] = (__bf16)lo[3];
        v[4] = (__bf16)hi[0]; v[5] = (__bf16)hi[1];
        v[6] = (__bf16)hi[2]; v[7] = (__bf16)hi[3];
        *reinterpret_cast<bf16x8*>(dst) = v;
    } else {
        *reinterpret_cast<u16x8*>(dst) =
            *reinterpret_cast<const u16x8*>((const unsigned short*)src);
    }
}

// GATED=1: W is (4H x K) f32; only gates {i,g,o} (row offsets 0,2H,3H) are
// staged; 128x96 gate-tile (fragment-col == gate) -> per-lane activation,
// writes bf16 h (M x N). GATED=0: plain 128x128 GEMM + bias, f32 output.
// AF32: A is f32 (layer 0's x) vs bf16 (h0/h1 in ws).
template <int GATED, int AF32>
__global__ __launch_bounds__(256) void gemm_fused(
    const void* __restrict__ Av,      // M x K, f32 if AF32 else bf16
    const float* __restrict__ W,      // (4H or N) x K f32
    const float* __restrict__ b0,     // b_ih (4H) or b_dec (N)
    const float* __restrict__ b1,     // b_hh (4H) or nullptr
    void* __restrict__ Ov,            // M x N: bf16 (GATED) or f32
    int M, int K, int N, int NBX)
{
    constexpr int NF    = GATED ? 3 : 4;    // fragment cols per wave
    constexpr int WCS   = GATED ? 48 : 64;  // wave B-row span
    constexpr int BROWS = GATED ? 96 : 128; // B tile rows
    constexpr int BCH   = BROWS / 32;       // B chunks per thread

    __shared__ __align__(16) unsigned short sA[BM * BK];
    __shared__ __align__(16) unsigned short sB[BROWS * BK];

    const int tid  = threadIdx.x;
    const int lane = tid & 63;
    const int w    = tid >> 6;
    const int wr   = w >> 1, wc = w & 1;
    const int l16  = lane & 15, hi8 = lane >> 4;

    // Bijective XCD-aware swizzle (all grids are multiples of 8): consecutive
    // rid within an XCD share one A row-panel -> L2 locality.
    const int nwg  = gridDim.x;
    const int cpx  = nwg >> 3;
    const int orig = blockIdx.x;
    const int rid  = (orig & 7) * cpx + (orig >> 3);
    const int bx   = rid % NBX;
    const int by   = rid / NBX;

    const int row0 = by * BM;
    const int n0   = GATED ? bx * 32 : bx * 128;

    // Staging descriptors. Chunk ch -> (row r = ch>>3, k-slot = ch&7).
    // LDS physical slot = slot ^ (r&7) (XOR swizzle, both sides identical).
    size_t gAo[4]; unsigned short* lA[4];
#pragma unroll
    for (int i = 0; i < 4; ++i) {
        int ch = tid + i * 256;
        int r = ch >> 3, slot = ch & 7;
        lA[i]  = sA + r * BK + (slot ^ (r & 7)) * 8;
        gAo[i] = (size_t)(row0 + r) * K + slot * 8;
    }
    size_t gBo[BCH]; unsigned short* lB[BCH];
#pragma unroll
    for (int i = 0; i < BCH; ++i) {
        int ch = tid + i * 256;
        int r = ch >> 3, slot = ch & 7;
        lB[i] = sB + r * BK + (slot ^ (r & 7)) * 8;
        int wrow;
        if (GATED) {
            int gate = (r % WCS) >> 4;               // 0,1,2 -> i,g,o
            int goff = (gate == 0) ? 0 : (gate + 1); // row offsets {0,2H,3H}
            int hcol = n0 + (r / WCS) * 16 + (r & 15);
            wrow = goff * N + hcol;
        } else {
            wrow = n0 + r;
        }
        gBo[i] = (size_t)wrow * K + slot * 8;
    }

    f32x4 acc[4][NF];
#pragma unroll
    for (int m = 0; m < 4; ++m)
#pragma unroll
        for (int n = 0; n < NF; ++n)
            acc[m][n] = (f32x4){0.f, 0.f, 0.f, 0.f};

    for (int k0 = 0; k0 < K; k0 += BK) {
#pragma unroll
        for (int i = 0; i < 4; ++i) {
            const void* src = AF32
                ? (const void*)((const float*)Av + gAo[i] + k0)
                : (const void*)((const unsigned short*)Av + gAo[i] + k0);
            stage_chunk<AF32>(src, lA[i]);
        }
#pragma unroll
        for (int i = 0; i < BCH; ++i)
            stage_chunk<1>((const void*)(W + gBo[i] + k0), lB[i]);
        __syncthreads();

#pragma unroll
        for (int ks = 0; ks < 2; ++ks) {
            bf16x8 av[4], bv[NF];
#pragma unroll
            for (int m = 0; m < 4; ++m) {
                int row = wr * 64 + m * 16 + l16;
                int ps = (ks * 4 + hi8) ^ (row & 7);
                av[m] = *reinterpret_cast<const bf16x8*>(sA + row * BK + ps * 8);
            }
#pragma unroll
            for (int n = 0; n < NF; ++n) {
                int row = wc * WCS + n * 16 + l16;
                int ps = (ks * 4 + hi8) ^ (row & 7);
                bv[n] = *reinterpret_cast<const bf16x8*>(sB + row * BK + ps * 8);
            }
#pragma unroll
            for (int m = 0; m < 4; ++m)
#pragma unroll
                for (int n = 0; n < NF; ++n)
                    acc[m][n] = __builtin_amdgcn_mfma_f32_16x16x32_bf16(
                        av[m], bv[n], acc[m][n], 0, 0, 0);
        }
        __syncthreads();
    }

    // ---- epilogue ----
    if (GATED) {
        unsigned short* O = (unsigned short*)Ov;
        const int hcol = n0 + wc * 16 + l16;          // fragment col = lane&15
        const float bi = b0[hcol]         + b1[hcol];
        const float bg = b0[2 * N + hcol] + b1[2 * N + hcol];
        const float bo = b0[3 * N + hcol] + b1[3 * N + hcol];
#pragma unroll
        for (int m = 0; m < 4; ++m) {
            int rbase = row0 + wr * 64 + m * 16 + hi8 * 4;
#pragma unroll
            for (int q = 0; q < 4; ++q) {
                float iv = sigf(acc[m][0][q] + bi);
                float gv = tanh_safe(acc[m][1][q] + bg);
                float ov = sigf(acc[m][2][q] + bo);
                float h  = ov * tanh_safe(iv * gv);
                O[(size_t)(rbase + q) * N + hcol] = f2b(h);
            }
        }
    } else {
        float* O = (float*)Ov;
#pragma unroll
        for (int n = 0; n < 4; ++n) {
            int col = n0 + wc * 64 + n * 16 + l16;
            float bias = b0[col];
#pragma unroll
            for (int m = 0; m < 4; ++m) {
                int rbase = row0 + wr * 64 + m * 16 + hi8 * 4;
#pragma unroll
                for (int q = 0; q < 4; ++q)
                    O[(size_t)(rbase + q) * N + col] = acc[m][n][q] + bias;
            }
        }
    }
}

extern "C" void kernel_launch(void* const* d_in, const int* in_sizes, int n_in,
                              void* d_out, int out_size, void* d_ws, size_t ws_size,
                              hipStream_t stream) {
    constexpr int M = 16384, D = 512, H = 1024;

    const float* x    = (const float*)d_in[0];
    const float* Wih0 = (const float*)d_in[1];
    // d_in[2] = W_hh0: unused (h0 = 0)
    const float* bih0 = (const float*)d_in[3];
    const float* bhh0 = (const float*)d_in[4];
    const float* Wih1 = (const float*)d_in[5];
    // d_in[6] = W_hh1: unused
    const float* bih1 = (const float*)d_in[7];
    const float* bhh1 = (const float*)d_in[8];
    const float* Wdec = (const float*)d_in[9];
    const float* bdec = (const float*)d_in[10];

    unsigned short* h0 = (unsigned short*)d_ws;        // M*H bf16
    unsigned short* h1 = h0 + (size_t)M * H;           // M*H bf16

    // layer 0: A = x (f32), K=512
    gemm_fused<1, 1><<<dim3((H / 32) * (M / BM)), 256, 0, stream>>>(
        x, Wih0, bih0, bhh0, h0, M, D, H, H / 32);
    // layer 1: A = h0 (bf16), K=1024
    gemm_fused<1, 0><<<dim3((H / 32) * (M / BM)), 256, 0, stream>>>(
        h0, Wih1, bih1, bhh1, h1, M, H, H, H / 32);
    // decoder: A = h1 (bf16), N=512, f32 output
    gemm_fused<0, 0><<<dim3((D / 128) * (M / BM)), 256, 0, stream>>>(
        h1, Wdec, bdec, nullptr, (float*)d_out, M, H, D, D / 128);
}

// Round 3
// 252.320 us; speedup vs baseline: 1.5448x; 1.5448x over previous
//
#include <hip/hip_runtime.h>
#include <stdint.h>

// LSTMBaseline: 2-layer, 1-step LSTM (zero init state) + decoder on MI355X.
//   h0 = lstm(x; W_ih0, b_ih0+b_hh0)      M=16384, K=512,  H=1024
//   h1 = lstm(h0; W_ih1, b_ih1+b_hh1)     K=1024
//   out = h1 @ W_dec^T + b_dec            N=512  (f32 out)
// All tensors f32. Round 3: pre-convert x / gate-packed W / Wdec to bf16 in
// d_ws (one cheap memory-bound pass), then run m97-structure MFMA GEMMs with
// global_load_lds width=16 (linear LDS dest + pre-swizzled global source).
// Algebraic cuts: f-gate dead (c0=0), W_hh dead (h0=0).

typedef __attribute__((ext_vector_type(8))) __bf16 bf16x8;
typedef __attribute__((ext_vector_type(8))) unsigned short u16x8;
typedef __attribute__((ext_vector_type(4))) float f32x4;

#define BM 128
#define BK 64

__device__ __forceinline__ unsigned short f2b(float f) {
    unsigned int x = __builtin_bit_cast(unsigned int, f);
    x = x + 0x7FFFu + ((x >> 16) & 1u);   // RNE
    return (unsigned short)(x >> 16);
}
__device__ __forceinline__ float sigf(float x) { return 1.0f / (1.0f + __expf(-x)); }
__device__ __forceinline__ float tanh_safe(float x) {
    float a = fabsf(x);
    float e = __expf(-2.0f * a);
    float t = (1.0f - e) / (1.0f + e);
    return x < 0.0f ? -t : t;
}

__device__ __forceinline__ void cvt8(const float* __restrict__ s,
                                     unsigned short* __restrict__ d) {
    f32x4 lo = *reinterpret_cast<const f32x4*>(s);
    f32x4 hi = *reinterpret_cast<const f32x4*>(s + 4);
    u16x8 v;
    v[0] = f2b(lo[0]); v[1] = f2b(lo[1]); v[2] = f2b(lo[2]); v[3] = f2b(lo[3]);
    v[4] = f2b(hi[0]); v[5] = f2b(hi[1]); v[6] = f2b(hi[2]); v[7] = f2b(hi[3]);
    *reinterpret_cast<u16x8*>(d) = v;
}

__device__ __forceinline__ void gload16(const void* g, void* l) {
    __builtin_amdgcn_global_load_lds(
        (const __attribute__((address_space(1))) void*)g,
        (__attribute__((address_space(3))) void*)l,
        16, 0, 0);
}

// ---- pre-pass: f32 -> bf16 linear convert -------------------------------
__global__ __launch_bounds__(256) void cvt_lin(const float* __restrict__ s,
                                               unsigned short* __restrict__ d,
                                               int n8) {
    int stride = gridDim.x * blockDim.x;
    for (int c = blockIdx.x * blockDim.x + threadIdx.x; c < n8; c += stride)
        cvt8(s + (size_t)c * 8, d + (size_t)c * 8);
}

// ---- pre-pass: gate-pack W (4H x K f32) -> (H/32 groups x 96 x K) bf16 ---
// Packed row p (group g, r=p%96): gate=(r%48)>>4 -> {i,g,o}; src row =
// {0,2H,3H}[gate] + g*32 + (r/48)*16 + (r&15). Matches the GEMM B-tile order.
__global__ __launch_bounds__(256) void pack_w(const float* __restrict__ W,
                                              unsigned short* __restrict__ d,
                                              int K8, int H, int n8) {
    int stride = gridDim.x * blockDim.x;
    for (int c = blockIdx.x * blockDim.x + threadIdx.x; c < n8; c += stride) {
        int dstRow = c / K8, kc = c - dstRow * K8;
        int group = dstRow / 96, r = dstRow - group * 96;
        int gate = (r % 48) >> 4;
        int goff = (gate == 0) ? 0 : (gate + 1);
        int hcol = group * 32 + (r / 48) * 16 + (r & 15);
        cvt8(W + ((size_t)(goff * H + hcol) * K8 + kc) * 8, d + (size_t)c * 8);
    }
}

// ---- fused GEMM ----------------------------------------------------------
// GATED=1: 128x(NF*32) gate-tile (fragment-col == gate), per-lane activation,
//          bf16 h out (M x N). GATED=0: plain GEMM + bias, f32 out.
// AK:    1 = A bf16 via global_load_lds, 0 = A f32 reg-staged.
// BMODE: 1 = W packed bf16 via global_load_lds, 0 = W f32 reg-staged gather.
// NF = fragment cols per wave (gated: 3 = gates i/g/o; decoder: 2).
template <int GATED, int AK, int BMODE, int NF>
__global__ __launch_bounds__(256) void gemm_fused(
    const void* __restrict__ Av,
    const void* __restrict__ Wv,
    const float* __restrict__ b0,
    const float* __restrict__ b1,
    void* __restrict__ Ov,
    int M, int K, int N, int NBX)
{
    constexpr int WCS   = NF * 16;           // wave B-row span
    constexpr int BROWS = NF * 32;           // B tile rows
    constexpr int ONB   = GATED ? 32 : BROWS; // output cols per block

    __shared__ __align__(16) unsigned short sA[BM * BK];
    __shared__ __align__(16) unsigned short sB[BROWS * BK];

    const int tid  = threadIdx.x;
    const int lane = tid & 63;
    const int w    = tid >> 6;
    const int wr   = w >> 1, wc = w & 1;
    const int l16  = lane & 15, hi8 = lane >> 4;

    // Bijective XCD swizzle (all grids %8==0): consecutive rid on one XCD
    // share an A row-panel; W stays L2-resident per XCD.
    const int cpx  = gridDim.x >> 3;
    const int orig = blockIdx.x;
    const int rid  = (orig & 7) * cpx + (orig >> 3);
    const int bx   = rid % NBX;
    const int by   = rid / NBX;

    const int row0 = by * BM;
    const int n0   = bx * ONB;

    // A staging: 1024 chunks (r=ch>>3, slot=ch&7). Swizzle: physical slot p
    // holds logical slot p^(r&7). AK=1: linear LDS dest + swizzled global
    // source (global_load_lds rule); AK=0: swizzled LDS dest.
    const unsigned short* gA16[4];
    const float*          gA32[4];
    unsigned short*       lA[4];
#pragma unroll
    for (int i = 0; i < 4; ++i) {
        int ch = tid + i * 256, r = ch >> 3, slot = ch & 7, ls = slot ^ (r & 7);
        if constexpr (AK) {
            lA[i]   = sA + ch * 8;
            gA16[i] = (const unsigned short*)Av + (size_t)(row0 + r) * K + ls * 8;
        } else {
            lA[i]   = sA + r * BK + ls * 8;
            gA32[i] = (const float*)Av + (size_t)(row0 + r) * K + slot * 8;
        }
    }
    const unsigned short* gB16[NF];
    const float*          gB32[NF];
    unsigned short*       lB[NF];
#pragma unroll
    for (int i = 0; i < NF; ++i) {
        int ch = tid + i * 256, r = ch >> 3, slot = ch & 7, ls = slot ^ (r & 7);
        if constexpr (BMODE) {
            lB[i]   = sB + ch * 8;
            int prow = GATED ? bx * BROWS + r : n0 + r;
            gB16[i] = (const unsigned short*)Wv + (size_t)prow * K + ls * 8;
        } else {
            lB[i] = sB + r * BK + ls * 8;
            int wrow;
            if (GATED) {
                int gate = (r % WCS) >> 4;
                int goff = (gate == 0) ? 0 : (gate + 1);
                int hcol = n0 + (r / WCS) * 16 + (r & 15);
                wrow = goff * N + hcol;
            } else {
                wrow = n0 + r;
            }
            gB32[i] = (const float*)Wv + (size_t)wrow * K + slot * 8;
        }
    }

    f32x4 acc[4][NF];
#pragma unroll
    for (int m = 0; m < 4; ++m)
#pragma unroll
        for (int n = 0; n < NF; ++n)
            acc[m][n] = (f32x4){0.f, 0.f, 0.f, 0.f};

    for (int k0 = 0; k0 < K; k0 += BK) {
#pragma unroll
        for (int i = 0; i < 4; ++i) {
            if constexpr (AK) gload16(gA16[i] + k0, lA[i]);
            else              cvt8(gA32[i] + k0, lA[i]);
        }
#pragma unroll
        for (int i = 0; i < NF; ++i) {
            if constexpr (BMODE) gload16(gB16[i] + k0, lB[i]);
            else                 cvt8(gB32[i] + k0, lB[i]);
        }
        __syncthreads();   // compiler drains vmcnt+lgkmcnt here

#pragma unroll
        for (int ks = 0; ks < 2; ++ks) {
            bf16x8 av[4], bv[NF];
#pragma unroll
            for (int m = 0; m < 4; ++m) {
                int row = wr * 64 + m * 16 + l16;
                int ps = (ks * 4 + hi8) ^ (row & 7);
                av[m] = *reinterpret_cast<const bf16x8*>(sA + row * BK + ps * 8);
            }
#pragma unroll
            for (int n = 0; n < NF; ++n) {
                int row = wc * WCS + n * 16 + l16;
                int ps = (ks * 4 + hi8) ^ (row & 7);
                bv[n] = *reinterpret_cast<const bf16x8*>(sB + row * BK + ps * 8);
            }
#pragma unroll
            for (int m = 0; m < 4; ++m)
#pragma unroll
                for (int n = 0; n < NF; ++n)
                    acc[m][n] = __builtin_amdgcn_mfma_f32_16x16x32_bf16(
                        av[m], bv[n], acc[m][n], 0, 0, 0);
        }
        __syncthreads();
    }

    // ---- epilogue ----
    if constexpr (GATED) {
        unsigned short* O = (unsigned short*)Ov;
        const int hcol = n0 + wc * 16 + l16;
        const float bi = b0[hcol]         + b1[hcol];
        const float bg = b0[2 * N + hcol] + b1[2 * N + hcol];
        const float bo = b0[3 * N + hcol] + b1[3 * N + hcol];
#pragma unroll
        for (int m = 0; m < 4; ++m) {
            int rbase = row0 + wr * 64 + m * 16 + hi8 * 4;
#pragma unroll
            for (int q = 0; q < 4; ++q) {
                float iv = sigf(acc[m][0][q] + bi);
                float gv = tanh_safe(acc[m][1][q] + bg);
                float ov = sigf(acc[m][2][q] + bo);
                float h  = ov * tanh_safe(iv * gv);
                O[(size_t)(rbase + q) * N + hcol] = f2b(h);
            }
        }
    } else {
        float* O = (float*)Ov;
#pragma unroll
        for (int n = 0; n < NF; ++n) {
            int col = n0 + wc * WCS + n * 16 + l16;
            float bias = b0[col];
#pragma unroll
            for (int m = 0; m < 4; ++m) {
                int rbase = row0 + wr * 64 + m * 16 + hi8 * 4;
#pragma unroll
                for (int q = 0; q < 4; ++q)
                    O[(size_t)(rbase + q) * N + col] = acc[m][n][q] + bias;
            }
        }
    }
}

extern "C" void kernel_launch(void* const* d_in, const int* in_sizes, int n_in,
                              void* d_out, int out_size, void* d_ws, size_t ws_size,
                              hipStream_t stream) {
    constexpr int M = 16384, D = 512, H = 1024;

    const float* x    = (const float*)d_in[0];
    const float* Wih0 = (const float*)d_in[1];
    // d_in[2] = W_hh0: unused (h0 = 0)
    const float* bih0 = (const float*)d_in[3];
    const float* bhh0 = (const float*)d_in[4];
    const float* Wih1 = (const float*)d_in[5];
    // d_in[6] = W_hh1: unused
    const float* bih1 = (const float*)d_in[7];
    const float* bhh1 = (const float*)d_in[8];
    const float* Wdec = (const float*)d_in[9];
    const float* bdec = (const float*)d_in[10];

    const size_t szH = (size_t)M * H * 2;          // 33.5 MB
    const size_t sw0 = (size_t)3 * H * D * 2;      // 3.1 MB
    const size_t sw1 = (size_t)3 * H * H * 2;      // 6.3 MB
    const size_t swd = (size_t)D * H * 2;          // 1.0 MB

    unsigned short* h0 = (unsigned short*)d_ws;
    unsigned short* h1 = (unsigned short*)((char*)d_ws + szH);
    unsigned short* xb = h1;                       // alias: dead before L1 writes h1
    unsigned short* wp0   = (unsigned short*)((char*)d_ws + 2 * szH);
    unsigned short* wp1   = (unsigned short*)((char*)wp0 + sw0);
    unsigned short* wdecb = (unsigned short*)((char*)wp1 + sw1);

    const bool packed = ws_size >= 2 * szH + sw0 + sw1 + swd;

    if (packed) {
        cvt_lin<<<2048, 256, 0, stream>>>(x, xb, M * D / 8);
        pack_w <<<768,  256, 0, stream>>>(Wih0, wp0, D / 8, H, 3 * H * D / 8);
        pack_w <<<1536, 256, 0, stream>>>(Wih1, wp1, H / 8, H, 3 * H * H / 8);
        cvt_lin<<<256,  256, 0, stream>>>(Wdec, wdecb, D * H / 8);

        gemm_fused<1, 1, 1, 3><<<dim3((H / 32) * (M / BM)), 256, 0, stream>>>(
            xb, wp0, bih0, bhh0, h0, M, D, H, H / 32);
        gemm_fused<1, 1, 1, 3><<<dim3((H / 32) * (M / BM)), 256, 0, stream>>>(
            h0, wp1, bih1, bhh1, h1, M, H, H, H / 32);
        gemm_fused<0, 1, 1, 2><<<dim3((D / 64) * (M / BM)), 256, 0, stream>>>(
            h1, wdecb, bdec, nullptr, (float*)d_out, M, H, D, D / 64);
    } else {
        // Fallback (ws too small for weight buffers): round-2-style staging.
        gemm_fused<1, 0, 0, 3><<<dim3((H / 32) * (M / BM)), 256, 0, stream>>>(
            x, Wih0, bih0, bhh0, h0, M, D, H, H / 32);
        gemm_fused<1, 1, 0, 3><<<dim3((H / 32) * (M / BM)), 256, 0, stream>>>(
            h0, Wih1, bih1, bhh1, h1, M, H, H, H / 32);
        gemm_fused<0, 1, 0, 2><<<dim3((D / 64) * (M / BM)), 256, 0, stream>>>(
            h1, Wdec, bdec, nullptr, (float*)d_out, M, H, D, D / 64);
    }
}